// Round 1
// baseline (448.203 us; speedup 1.0000x reference)
//
#include <hip/hip_runtime.h>
#include <math.h>

#define HIDDEN 128
#define IDIM   50000
#define STEPS  100

// ws layout (float offsets)
#define WS_E1   0        // 128   e1acc = W_enc@x0
#define WS_C    128      // 128   cacc  = W_enc@b_dec
#define WS_M    256      // 16384 M = W_enc@W_dec (128x128)
#define WS_P    16640    // 49152 P = W_ih@M (384x128)
#define WS_Q    65792    // 384   q = W_ih@(c+b_enc)+b_ih
#define WS_IG1  66176    // 384   ig1 = W_ih@(e1+b_enc)+b_ih
#define WS_HT   66560    // 16384 H_T[i][k] (128x128, cols 0..99 used)

__device__ __forceinline__ float sigmoidf_(float x){ return 1.0f/(1.0f+expf(-x)); }

__global__ void k_zero(float* __restrict__ ws){
  ws[threadIdx.x] = 0.0f;   // 256 threads: e1acc + cacc
}

// e1acc[r] = dot(W_enc[r,:], x0); cacc[r] = dot(W_enc[r,:], b_dec)
// 256 blocks: 2 per row (half the K range each), block-reduce + atomicAdd
__global__ __launch_bounds__(256) void k_enc(const float* __restrict__ W_enc,
    const float* __restrict__ x0, const float* __restrict__ b_dec,
    float* __restrict__ ws)
{
  const int r    = blockIdx.x >> 1;
  const int half = blockIdx.x & 1;
  const float4* wr = (const float4*)(W_enc + (size_t)r*IDIM + half*25000);
  const float4* xv = (const float4*)(x0   + half*25000);
  const float4* bv = (const float4*)(b_dec + half*25000);
  float s0 = 0.f, s1 = 0.f;
  for (int i = threadIdx.x; i < 6250; i += 256){
    float4 w = wr[i]; float4 a = xv[i]; float4 b = bv[i];
    s0 += w.x*a.x + w.y*a.y + w.z*a.z + w.w*a.w;
    s1 += w.x*b.x + w.y*b.y + w.z*b.z + w.w*b.w;
  }
  __shared__ float r0[256], r1[256];
  r0[threadIdx.x] = s0; r1[threadIdx.x] = s1;
  __syncthreads();
  for (int off = 128; off > 0; off >>= 1){
    if (threadIdx.x < off){
      r0[threadIdx.x] += r0[threadIdx.x+off];
      r1[threadIdx.x] += r1[threadIdx.x+off];
    }
    __syncthreads();
  }
  if (threadIdx.x == 0){
    atomicAdd(&ws[WS_E1 + r], r0[0]);
    atomicAdd(&ws[WS_C  + r], r1[0]);
  }
}

// M partials: 500 blocks, each K-chunk of 100; 128x128 tile, 8x8 micro-tile.
// Partials land in scratch (= d_out, free until k_decode).
__global__ __launch_bounds__(256) void k_gemmM(const float* __restrict__ W_enc,
    const float* __restrict__ W_dec, float* __restrict__ scratch)
{
  __shared__ __align__(16) float As[4][128];
  __shared__ __align__(16) float Bs[4][128];
  const int t  = threadIdx.x;
  const int tx = t & 15, ty = t >> 4;
  const int d0 = blockIdx.x * 100;
  float acc[8][8];
  #pragma unroll
  for (int p = 0; p < 8; p++)
    #pragma unroll
    for (int q = 0; q < 8; q++) acc[p][q] = 0.f;

  for (int k0 = 0; k0 < 100; k0 += 4){
    __syncthreads();
    if (t < 128){
      float4 w = *(const float4*)(W_enc + (size_t)t*IDIM + d0 + k0);
      As[0][t] = w.x; As[1][t] = w.y; As[2][t] = w.z; As[3][t] = w.w;
    } else {
      int u = t - 128; int kk = u >> 5, g = u & 31;
      *(float4*)&Bs[kk][g*4] = *(const float4*)(W_dec + (size_t)(d0+k0+kk)*HIDDEN + g*4);
    }
    __syncthreads();
    #pragma unroll
    for (int kk = 0; kk < 4; kk++){
      float4 alo = *(const float4*)&As[kk][ty*8];
      float4 ahi = *(const float4*)&As[kk][ty*8+4];
      float4 blo = *(const float4*)&Bs[kk][tx*8];
      float4 bhi = *(const float4*)&Bs[kk][tx*8+4];
      float a[8] = {alo.x,alo.y,alo.z,alo.w,ahi.x,ahi.y,ahi.z,ahi.w};
      float b[8] = {blo.x,blo.y,blo.z,blo.w,bhi.x,bhi.y,bhi.z,bhi.w};
      #pragma unroll
      for (int p = 0; p < 8; p++)
        #pragma unroll
        for (int q = 0; q < 8; q++) acc[p][q] += a[p]*b[q];
    }
  }
  float* outp = scratch + (size_t)blockIdx.x * 16384;
  #pragma unroll
  for (int p = 0; p < 8; p++){
    #pragma unroll
    for (int q = 0; q < 8; q += 4){
      *(float4*)&outp[(ty*8+p)*128 + tx*8 + q] =
        make_float4(acc[p][q], acc[p][q+1], acc[p][q+2], acc[p][q+3]);
    }
  }
}

// Sum 500 partials -> M. 64 blocks x 256 threads, one (i,j) each.
__global__ __launch_bounds__(256) void k_reduceM(const float* __restrict__ scratch,
    float* __restrict__ Mout)
{
  const int idx = blockIdx.x * 256 + threadIdx.x;
  float s0=0.f, s1=0.f, s2=0.f, s3=0.f;
  for (int p = 0; p < 500; p += 4){
    s0 += scratch[(size_t)(p+0)*16384 + idx];
    s1 += scratch[(size_t)(p+1)*16384 + idx];
    s2 += scratch[(size_t)(p+2)*16384 + idx];
    s3 += scratch[(size_t)(p+3)*16384 + idx];
  }
  Mout[idx] = (s0+s1) + (s2+s3);
}

// P[r,:] = W_ih[r,:]@M ; q[r] = W_ih[r,:]@(cacc+b_enc)+b_ih[r];
// ig1[r] = W_ih[r,:]@(e1acc+b_enc)+b_ih[r]. 384 blocks x 128 threads.
__global__ __launch_bounds__(128) void k_smallP(const float* __restrict__ W_ih,
    const float* __restrict__ b_ih, const float* __restrict__ b_enc,
    const float* __restrict__ ws, const float* __restrict__ M,
    float* __restrict__ P, float* __restrict__ q, float* __restrict__ ig1)
{
  const int r = blockIdx.x, j = threadIdx.x;
  const float* wr = W_ih + (size_t)r * HIDDEN;
  float acc = 0.f;
  for (int k = 0; k < HIDDEN; k++) acc += wr[k] * M[k*HIDDEN + j];
  P[(size_t)r*HIDDEN + j] = acc;
  const float wj = wr[j];
  float t0 = wj * (ws[WS_C  + j] + b_enc[j]);
  float t1 = wj * (ws[WS_E1 + j] + b_enc[j]);
  __shared__ float r0[128], r1[128];
  r0[j] = t0; r1[j] = t1;
  __syncthreads();
  for (int off = 64; off > 0; off >>= 1){
    if (j < off){ r0[j] += r0[j+off]; r1[j] += r1[j+off]; }
    __syncthreads();
  }
  if (j == 0){
    q[r]   = r0[0] + b_ih[r];
    ig1[r] = r1[0] + b_ih[r];
  }
}

// h_1 from ig1 (h_0 = 0 => hg = 0): writes H_T[:,0]
__global__ void k_h1(const float* __restrict__ ig1, const float* __restrict__ b_n,
                     float* __restrict__ H_T)
{
  const int i = threadIdx.x;  // 128
  float reset = sigmoidf_(ig1[i]);
  float inp   = sigmoidf_(ig1[128+i]);
  float nw    = tanhf(ig1[256+i] + reset * b_n[i]);
  H_T[(size_t)i*HIDDEN] = nw + inp * (0.f - nw);
}

// The sequential recurrence. 1 block, 768 threads: thread t owns row t of
// [P; W_hh] in 128 VGPRs. h broadcast from LDS; 2 barriers/step; 99 steps.
__global__ __launch_bounds__(768) void k_recur(const float* __restrict__ P,
    const float* __restrict__ W_hh, const float* __restrict__ q,
    const float* __restrict__ b_n, float* __restrict__ H_T)
{
  const int t = threadIdx.x;
  float4 wv[32];
  float qq;
  if (t < 384){
    const float4* src = (const float4*)(P + (size_t)t * HIDDEN);
    #pragma unroll
    for (int j = 0; j < 32; j++) wv[j] = src[j];
    qq = q[t];
  } else {
    const float4* src = (const float4*)(W_hh + (size_t)(t-384) * HIDDEN);
    #pragma unroll
    for (int j = 0; j < 32; j++) wv[j] = src[j];
    qq = 0.f;
  }
  __shared__ __align__(16) float h[HIDDEN];
  __shared__ float z[768];
  __shared__ float bn[HIDDEN];
  if (t < HIDDEN){ h[t] = H_T[(size_t)t*HIDDEN]; bn[t] = b_n[t]; }
  __syncthreads();
  for (int k = 1; k < STEPS; k++){
    float acc = qq;
    const float4* h4 = (const float4*)h;
    #pragma unroll
    for (int j = 0; j < 32; j++){
      float4 hv = h4[j];
      acc += wv[j].x*hv.x + wv[j].y*hv.y + wv[j].z*hv.z + wv[j].w*hv.w;
    }
    z[t] = acc;
    __syncthreads();
    if (t < HIDDEN){
      float reset = sigmoidf_(z[t]       + z[384+t]);
      float inp   = sigmoidf_(z[128+t]   + z[512+t]);
      float nw    = tanhf(z[256+t] + reset*(z[640+t] + bn[t]));
      float hn    = nw + inp*(h[t] - nw);
      H_T[(size_t)t*HIDDEN + k] = hn;
      h[t] = hn;        // only other threads read h, and only after barrier below
    }
    __syncthreads();
  }
}

// X[k][d] = W_dec[d,:]@h_k + b_dec[d]; write samples/means/sigmas.
// Tile 64 d x 64 k, micro 4x4; H-tile in LDS, W_dec via L1; float4 stores.
__global__ __launch_bounds__(256) void k_decode(const float* __restrict__ W_dec,
    const float* __restrict__ b_dec, const float* __restrict__ H_T,
    float* __restrict__ out)
{
  __shared__ __align__(16) float Bs[128][68];
  const int t  = threadIdx.x;
  const int tx = t & 15, ty = t >> 4;
  const int d0 = blockIdx.x * 64;
  const int k0 = blockIdx.y * 64;

  // stage H_T[:, k0:k0+64] -> Bs (128 rows x 16 float4)
  for (int l = t; l < 2048; l += 256){
    int j = l >> 4, g = l & 15;
    *(float4*)&Bs[j][g*4] = *(const float4*)&H_T[(size_t)j*HIDDEN + k0 + g*4];
  }
  __syncthreads();

  const int d  = d0 + tx*4;               // always a multiple of 4
  const int dc = (d < IDIM) ? d : 0;      // clamp: garbage rows never stored
  const float* A0 = W_dec + (size_t)dc * HIDDEN;
  const float* A1 = A0 + HIDDEN;
  const float* A2 = A1 + HIDDEN;
  const float* A3 = A2 + HIDDEN;

  float acc[4][4];
  #pragma unroll
  for (int p = 0; p < 4; p++)
    #pragma unroll
    for (int q = 0; q < 4; q++) acc[p][q] = 0.f;

  for (int j0 = 0; j0 < HIDDEN; j0 += 4){
    float4 a0 = *(const float4*)(A0 + j0);
    float4 a1 = *(const float4*)(A1 + j0);
    float4 a2 = *(const float4*)(A2 + j0);
    float4 a3 = *(const float4*)(A3 + j0);
    #pragma unroll
    for (int jj = 0; jj < 4; jj++){
      float4 b = *(const float4*)&Bs[j0+jj][ty*4];
      float e0 = (jj==0)?a0.x:(jj==1)?a0.y:(jj==2)?a0.z:a0.w;
      float e1 = (jj==0)?a1.x:(jj==1)?a1.y:(jj==2)?a1.z:a1.w;
      float e2 = (jj==0)?a2.x:(jj==1)?a2.y:(jj==2)?a2.z:a2.w;
      float e3 = (jj==0)?a3.x:(jj==1)?a3.y:(jj==2)?a3.z:a3.w;
      acc[0][0] += e0*b.x; acc[0][1] += e0*b.y; acc[0][2] += e0*b.z; acc[0][3] += e0*b.w;
      acc[1][0] += e1*b.x; acc[1][1] += e1*b.y; acc[1][2] += e1*b.z; acc[1][3] += e1*b.w;
      acc[2][0] += e2*b.x; acc[2][1] += e2*b.y; acc[2][2] += e2*b.z; acc[2][3] += e2*b.w;
      acc[3][0] += e3*b.x; acc[3][1] += e3*b.y; acc[3][2] += e3*b.z; acc[3][3] += e3*b.w;
    }
  }

  if (d < IDIM){   // d multiple of 4 => d+3 <= 49999 whenever d < 50000
    float4 bd = *(const float4*)&b_dec[d];
    const size_t SO = (size_t)STEPS * IDIM;  // 5,000,000
    #pragma unroll
    for (int q = 0; q < 4; q++){
      int k = k0 + ty*4 + q;
      if (k < STEPS){
        float4 v = make_float4(acc[0][q]+bd.x, acc[1][q]+bd.y,
                               acc[2][q]+bd.z, acc[3][q]+bd.w);
        size_t o = (size_t)k * IDIM + d;
        *(float4*)&out[o]        = v;                       // samples
        *(float4*)&out[o + SO]   = v;                       // means
        *(float4*)&out[o + 2*SO] = make_float4(0.f,0.f,0.f,0.f); // sigmas
      }
    }
  }
}

extern "C" void kernel_launch(void* const* d_in, const int* in_sizes, int n_in,
                              void* d_out, int out_size, void* d_ws, size_t ws_size,
                              hipStream_t stream) {
  const float* x0    = (const float*)d_in[0];
  const float* W_enc = (const float*)d_in[1];
  const float* b_enc = (const float*)d_in[2];
  const float* W_ih  = (const float*)d_in[3];
  const float* W_hh  = (const float*)d_in[4];
  const float* b_ih  = (const float*)d_in[5];
  const float* b_n   = (const float*)d_in[6];
  const float* W_dec = (const float*)d_in[7];
  const float* b_dec = (const float*)d_in[8];
  (void)in_sizes; (void)n_in; (void)out_size; (void)ws_size;

  float* out = (float*)d_out;
  float* ws  = (float*)d_ws;
  float* M   = ws + WS_M;
  float* P   = ws + WS_P;
  float* q   = ws + WS_Q;
  float* ig1 = ws + WS_IG1;
  float* H_T = ws + WS_HT;
  float* scratch = out;   // 500*16384 floats = 32 MB of d_out, dead until k_decode

  hipLaunchKernelGGL(k_zero,    dim3(1),      dim3(256), 0, stream, ws);
  hipLaunchKernelGGL(k_enc,     dim3(256),    dim3(256), 0, stream, W_enc, x0, b_dec, ws);
  hipLaunchKernelGGL(k_gemmM,   dim3(500),    dim3(256), 0, stream, W_enc, W_dec, scratch);
  hipLaunchKernelGGL(k_reduceM, dim3(64),     dim3(256), 0, stream, scratch, M);
  hipLaunchKernelGGL(k_smallP,  dim3(384),    dim3(128), 0, stream, W_ih, b_ih, b_enc, ws, M, P, q, ig1);
  hipLaunchKernelGGL(k_h1,      dim3(1),      dim3(128), 0, stream, ig1, b_n, H_T);
  hipLaunchKernelGGL(k_recur,   dim3(1),      dim3(768), 0, stream, P, W_hh, q, b_n, H_T);
  hipLaunchKernelGGL(k_decode,  dim3(782, 2), dim3(256), 0, stream, W_dec, b_dec, H_T, out);
}